// Round 12
// baseline (180.569 us; speedup 1.0000x reference)
//
#include <hip/hip_runtime.h>

#define TSEQ 111
#define CT 8
#define NCH 14            // ceil(111/8) chunks; chunk 13 has 7 valid timesteps
#define NSS (NCH + 3)     // 17 supersteps (4-layer pipeline fill)
#define L2E 1.44269504088896340736f
#define TWO_L2E 2.88539008177792680472f

using f32x4  = __attribute__((ext_vector_type(4))) float;
using f32x2  = __attribute__((ext_vector_type(2))) float;
using short8 = __attribute__((ext_vector_type(8))) short;

union FragU { unsigned u[4]; uint4 v; short8 s; };

__device__ __forceinline__ float fexp2(float x) { return __builtin_amdgcn_exp2f(x); }
__device__ __forceinline__ float frcp(float x)  { return __builtin_amdgcn_rcpf(x); }
__device__ __forceinline__ float tanh2(float zs) { return 1.f - 2.f * frcp(1.f + fexp2(zs + zs)); }
__device__ __forceinline__ f32x2 exp2v(f32x2 x) { f32x2 r; r[0] = fexp2(x[0]); r[1] = fexp2(x[1]); return r; }
__device__ __forceinline__ f32x2 rcpv(f32x2 x)  { f32x2 r; r[0] = frcp(x[0]); r[1] = frcp(x[1]); return r; }

__device__ __forceinline__ unsigned rnd_bf16(float w) {
  unsigned u = __float_as_uint(w);
  return (u + 0x7fffu + ((u >> 16) & 1u)) >> 16;
}
__device__ __forceinline__ unsigned pk2(float a, float b) {
  return rnd_bf16(a) | (rnd_bf16(b) << 16);
}
__device__ __forceinline__ unsigned cvtpk(float a, float b) {
  unsigned r;
  asm("v_cvt_pk_bf16_f32 %0, %1, %2" : "=v"(r) : "v"(a), "v"(b));
  return r;
}

// CHUNKED DIAGONAL PIPELINE. Block = 4 waves (one per layer), 16 batch rows, CT=8
// timesteps per superstep. Wave l at superstep s processes chunk ch = s-l of layer l.
//
// pi-permuted hidden ordering: B-frag slot (q, j) holds unit (j<4 ? 4q+j : 16+4q+j-4).
// With C = mfma(A=W-tile, B=h): the 8 C-tiles give lane (c,q) gate values for exactly
// its own pi unit set {4q+e, 16+4q+e} of batch c -> h(t) repacks into the NEXT step's
// B-frag with 4 cvtpk, fully in-register. Own-layer recurrence never touches LDS.
// W (ih, hh) k-columns and Wa are pi-permuted at load; gate-dim order is standard.
//
// LDS: chunk buffers buf[2 parity][producer layer 0..2][CT][16 batch][4 qslot][8 units]
// bf16 (48 KB). Producer lane writes its fh (uint4) at [c][q]; consumer lane reads the
// same [c][q] -> identity mapping, slot-major, conflict-minimal. l3 output stays in-wave
// (attention); l0 input comes from emb via global loads (idx prefetched a chunk ahead).
// One lgkm-only barrier per superstep (17 total vs 115 before).
__global__ __launch_bounds__(256, 2) void lstm_fused(
    const int* __restrict__ x, const float* __restrict__ emb,
    const float* __restrict__ Wih, const float* __restrict__ Whh,
    const float* __restrict__ bih, const float* __restrict__ bhh,
    const float* __restrict__ Wa, const float* __restrict__ W1,
    const float* __restrict__ b1, const float* __restrict__ W2,
    const float* __restrict__ b2, float* __restrict__ out)
{
  __shared__ __align__(16) unsigned short buf[2 * 3 * CT * 512];  // 48 KB

  const int tid  = threadIdx.x;
  const int l    = __builtin_amdgcn_readfirstlane(tid) >> 6;  // layer 0..3 (SGPR)
  const int lane = tid & 63;
  const int c    = lane & 15;   // batch row in tile (B/C col); W-tile row (A)
  const int q    = lane >> 4;   // B-slot / C row-quad
  const int rowbase = blockIdx.x * 16;
  const int xrow = (rowbase + c) * TSEQ;

  // ---- weights -> A-frags (pi-permuted k-columns), RTN bf16, sign/scale folded
  FragU wih[8], whh[8];
  f32x4 bvv[8];
#pragma unroll
  for (int g = 0; g < 8; ++g) {
    const float sj = ((g >> 1) == 2) ? TWO_L2E : -L2E;   // gates i,f,g,o; g-gate: +2*l2e
    const int wr = 16 * g + c;
    const float* WI = Wih + l * 4096 + wr * 32;
    const float* WH = Whh + l * 4096 + wr * 32;
    float4 ia = *(const float4*)(WI + 4 * q);
    float4 ib = *(const float4*)(WI + 16 + 4 * q);
    float4 ha = *(const float4*)(WH + 4 * q);
    float4 hb = *(const float4*)(WH + 16 + 4 * q);
    wih[g].u[0] = pk2(ia.x * sj, ia.y * sj); wih[g].u[1] = pk2(ia.z * sj, ia.w * sj);
    wih[g].u[2] = pk2(ib.x * sj, ib.y * sj); wih[g].u[3] = pk2(ib.z * sj, ib.w * sj);
    whh[g].u[0] = pk2(ha.x * sj, ha.y * sj); whh[g].u[1] = pk2(ha.z * sj, ha.w * sj);
    whh[g].u[2] = pk2(hb.x * sj, hb.y * sj); whh[g].u[3] = pk2(hb.z * sj, hb.w * sj);
    const int bi = l * 128 + 16 * g + 4 * q;
#pragma unroll
    for (int e = 0; e < 4; ++e)
      bvv[g][e] = (bih[bi + e] + bhh[bi + e]) * sj;
  }

  // ---- Wa as row-replicated A-frag (pi columns), hi/lo split, l==3 only
  FragU wahA, walA;
#pragma unroll
  for (int p = 0; p < 4; ++p) { wahA.u[p] = 0u; walA.u[p] = 0u; }
  if (l == 3) {
    float wv[8];
    float4 wa0 = *(const float4*)(Wa + 4 * q);
    float4 wa1 = *(const float4*)(Wa + 16 + 4 * q);
    wv[0] = wa0.x; wv[1] = wa0.y; wv[2] = wa0.z; wv[3] = wa0.w;
    wv[4] = wa1.x; wv[5] = wa1.y; wv[6] = wa1.z; wv[7] = wa1.w;
#pragma unroll
    for (int p = 0; p < 4; ++p) {
      float w0 = wv[2 * p] * L2E, w1 = wv[2 * p + 1] * L2E;
      unsigned h0 = rnd_bf16(w0), h1 = rnd_bf16(w1);
      wahA.u[p] = h0 | (h1 << 16);
      float l0v = w0 - __uint_as_float(h0 << 16);
      float l1v = w1 - __uint_as_float(h1 << 16);
      walA.u[p] = rnd_bf16(l0v) | (rnd_bf16(l1v) << 16);
    }
  }

  // ---- per-lane state: cells for units {4q+e} (E) and {16+4q+e} (O), batch c
  f32x2 csE[2], csO[2];
  csE[0] = (f32x2){0.f, 0.f}; csE[1] = (f32x2){0.f, 0.f};
  csO[0] = (f32x2){0.f, 0.f}; csO[1] = (f32x2){0.f, 0.f};
  FragU fh;                       // own h(t-1) as B-frag, register-resident
  fh.u[0] = 0u; fh.u[1] = 0u; fh.u[2] = 0u; fh.u[3] = 0u;
  float mr = -1e30f, sr = 0.f;
  float cxE[4], cxO[4];
#pragma unroll
  for (int e = 0; e < 4; ++e) { cxE[e] = 0.f; cxO[e] = 0.f; }

  // ---- l0: indices for chunk 0
  int idxc[CT];
  if (l == 0) {
#pragma unroll
    for (int j = 0; j < CT; ++j) idxc[j] = x[xrow + j];
  }
  __syncthreads();

  for (int s = 0; s < NSS; ++s) {
    const int ch = s - l;
    const bool active = ((unsigned)ch < (unsigned)NCH);
    const int rp = (s + 1) & 1;   // read parity (producer wrote at s-1)
    const int wp = s & 1;         // write parity

    FragU fiU[CT];
    float4 emE[4], emO[4];
    int idxn[CT];

    if (l == 0) {
      if (active) {
        // issue first 4 emb gathers (units 4q..4q+3 and 16+4q..16+4q+3 = pi layout)
#pragma unroll
        for (int j = 0; j < 4; ++j) {
          emE[j] = *(const float4*)(emb + idxc[j] * 32 + 4 * q);
          emO[j] = *(const float4*)(emb + idxc[j] * 32 + 16 + 4 * q);
        }
        // prefetch next chunk's token indices (clamped)
#pragma unroll
        for (int j = 0; j < CT; ++j) {
          int tt = (ch + 1) * CT + j;
          tt = tt > TSEQ - 1 ? TSEQ - 1 : tt;
          idxn[j] = x[xrow + tt];
        }
      }
    } else if (active) {
      // read the whole input chunk upfront: 8x ds_read_b128
      const unsigned short* bp =
          buf + ((rp * 3 + (l - 1)) * CT) * 512 + c * 32 + q * 8;
#pragma unroll
      for (int j = 0; j < CT; ++j)
        fiU[j].v = *(const uint4*)(bp + j * 512);
    }

    if (active) {
#pragma unroll
      for (int tau = 0; tau < CT; ++tau) {
        // ---- fi(t)
        FragU fi;
        if (l == 0) {
          float4 eE = emE[tau & 3], eO = emO[tau & 3];
          fi.u[0] = cvtpk(eE.x, eE.y); fi.u[1] = cvtpk(eE.z, eE.w);
          fi.u[2] = cvtpk(eO.x, eO.y); fi.u[3] = cvtpk(eO.z, eO.w);
          if (tau + 4 < CT) {
            emE[tau & 3] = *(const float4*)(emb + idxc[tau + 4] * 32 + 4 * q);
            emO[tau & 3] = *(const float4*)(emb + idxc[tau + 4] * 32 + 16 + 4 * q);
          }
        } else {
          fi = fiU[tau];
        }

        // ---- gate MFMAs: 8 tiles x (ih + hh); C[gate row 16g+4q+e][batch c]
        f32x4 acc[8];
#pragma unroll
        for (int g = 0; g < 8; ++g)
          acc[g] = __builtin_amdgcn_mfma_f32_16x16x32_bf16(wih[g].s, fi.s, bvv[g], 0, 0, 0);
#pragma unroll
        for (int g = 0; g < 8; ++g)
          acc[g] = __builtin_amdgcn_mfma_f32_16x16x32_bf16(whh[g].s, fh.s, acc[g], 0, 0, 0);

        // ---- gates (packed f32): even units from acc[0,2,4,6], odd from acc[1,3,5,7]
        // acc(i)=-zi*l2e, (f)=-zf*l2e, (g)=+2zg*l2e, (o)=-zo*l2e
        float hvE[4], hvO[4];
        const f32x2 one = {1.f, 1.f};
        const f32x2 tl2 = {TWO_L2E, TWO_L2E};
#pragma unroll
        for (int p2 = 0; p2 < 2; ++p2) {
          const int e0 = 2 * p2;
          {
            f32x2 vi; vi[0] = acc[0][e0]; vi[1] = acc[0][e0 + 1];
            f32x2 vf; vf[0] = acc[2][e0]; vf[1] = acc[2][e0 + 1];
            f32x2 vg; vg[0] = acc[4][e0]; vg[1] = acc[4][e0 + 1];
            f32x2 vo; vo[0] = acc[6][e0]; vo[1] = acc[6][e0 + 1];
            f32x2 ea = exp2v(vi), em_ = exp2v(vf), eb = exp2v(vg), ep = exp2v(vo);
            f32x2 P  = (one + ea) * (one + eb);
            f32x2 M1 = one + em_;
            f32x2 cn = (csE[p2] * P + (eb - one) * M1) * rcpv(M1 * P);
            csE[p2] = cn;
            f32x2 qa = cn * tl2;
            qa[0] = fminf(qa[0], 80.f); qa[1] = fminf(qa[1], 80.f);
            f32x2 qv = exp2v(qa);
            f32x2 hvv = (qv - one) * rcpv((one + ep) * (one + qv));
            hvE[e0] = hvv[0]; hvE[e0 + 1] = hvv[1];
          }
          {
            f32x2 vi; vi[0] = acc[1][e0]; vi[1] = acc[1][e0 + 1];
            f32x2 vf; vf[0] = acc[3][e0]; vf[1] = acc[3][e0 + 1];
            f32x2 vg; vg[0] = acc[5][e0]; vg[1] = acc[5][e0 + 1];
            f32x2 vo; vo[0] = acc[7][e0]; vo[1] = acc[7][e0 + 1];
            f32x2 ea = exp2v(vi), em_ = exp2v(vf), eb = exp2v(vg), ep = exp2v(vo);
            f32x2 P  = (one + ea) * (one + eb);
            f32x2 M1 = one + em_;
            f32x2 cn = (csO[p2] * P + (eb - one) * M1) * rcpv(M1 * P);
            csO[p2] = cn;
            f32x2 qa = cn * tl2;
            qa[0] = fminf(qa[0], 80.f); qa[1] = fminf(qa[1], 80.f);
            f32x2 qv = exp2v(qa);
            f32x2 hvv = (qv - one) * rcpv((one + ep) * (one + qv));
            hvO[e0] = hvv[0]; hvO[e0 + 1] = hvv[1];
          }
        }

        // ---- h(t) -> B-frag (pi order), in-register
        fh.u[0] = cvtpk(hvE[0], hvE[1]); fh.u[1] = cvtpk(hvE[2], hvE[3]);
        fh.u[2] = cvtpk(hvO[0], hvO[1]); fh.u[3] = cvtpk(hvO[2], hvO[3]);

        // ---- publish for next layer (l<3): ONE ds_write_b128
        if (l < 3)
          *(uint4*)(buf + ((wp * 3 + l) * CT + tau) * 512 + c * 32 + q * 8) = fh.v;

        // ---- attention (l==3), t < 111
        if (l == 3 && ch * CT + tau < TSEQ) {
          f32x4 z = {0.f, 0.f, 0.f, 0.f};
          f32x4 sacc = __builtin_amdgcn_mfma_f32_16x16x32_bf16(wahA.s, fh.s, z, 0, 0, 0);
          sacc = __builtin_amdgcn_mfma_f32_16x16x32_bf16(walA.s, fh.s, sacc, 0, 0, 0);
          float pf = sacc[0];                 // score(batch c), replicated
          float mn = fmaxf(mr, pf);
          float scl = fexp2(mr - mn);
          float pr = fexp2(pf - mn);
          sr = sr * scl + pr;
#pragma unroll
          for (int e = 0; e < 4; ++e) {
            cxE[e] = cxE[e] * scl + pr * hvE[e];
            cxO[e] = cxO[e] * scl + pr * hvO[e];
          }
          mr = mn;
        }
      }
      if (l == 0) {
#pragma unroll
        for (int j = 0; j < CT; ++j) idxc[j] = idxn[j];
      }
    }

    // lgkm-only barrier: LDS synced; l0's global prefetches stay in flight
    asm volatile("s_waitcnt lgkmcnt(0)\n\ts_barrier" ::: "memory");
  }

  // ---- context -> LDS (fp32 [16][33]); l3 lane: batch c, units {4q+e, 16+4q+e}
  float* cb = (float*)buf;
  if (l == 3) {
    float inv = frcp(sr);
#pragma unroll
    for (int e = 0; e < 4; ++e) {
      cb[c * 33 + 4 * q + e]      = cxE[e] * inv;
      cb[c * 33 + 16 + 4 * q + e] = cxO[e] * inv;
    }
  }
  __syncthreads();
  if (l != 1) return;

  // ---- head (one wave): tanh MLP -> out, 16 rows
  float a0[4], a1[4];
  {
    float bb0 = b1[c], bb1 = b1[c + 16];
#pragma unroll
    for (int e = 0; e < 4; ++e) { a0[e] = bb0; a1[e] = bb1; }
    for (int j = 0; j < 32; ++j) {
      float w0 = W1[j * 32 + c];
      float w1 = W1[j * 32 + c + 16];
#pragma unroll
      for (int e = 0; e < 4; ++e) {
        float cr = cb[(4 * q + e) * 33 + j];
        a0[e] = fmaf(cr, w0, a0[e]);
        a1[e] = fmaf(cr, w1, a1[e]);
      }
    }
  }
  float o0[4], o1[4], o2[4];
  {
    float w20 = W2[c * 3 + 0], w21 = W2[c * 3 + 1], w22 = W2[c * 3 + 2];
    float w30 = W2[(c + 16) * 3 + 0], w31 = W2[(c + 16) * 3 + 1], w32 = W2[(c + 16) * 3 + 2];
#pragma unroll
    for (int e = 0; e < 4; ++e) {
      float h0 = tanh2(a0[e] * L2E);
      float hB = tanh2(a1[e] * L2E);
      o0[e] = h0 * w20 + hB * w30;
      o1[e] = h0 * w21 + hB * w31;
      o2[e] = h0 * w22 + hB * w32;
    }
  }
#pragma unroll
  for (int mk = 1; mk <= 8; mk <<= 1) {
#pragma unroll
    for (int e = 0; e < 4; ++e) {
      o0[e] += __shfl_xor(o0[e], mk, 64);
      o1[e] += __shfl_xor(o1[e], mk, 64);
      o2[e] += __shfl_xor(o2[e], mk, 64);
    }
  }
  if (c < 3) {
    float bb = b2[c];
#pragma unroll
    for (int e = 0; e < 4; ++e) {
      float v = (c == 0) ? o0[e] : ((c == 1) ? o1[e] : o2[e]);
      out[(rowbase + 4 * q + e) * 3 + c] = v + bb;
    }
  }
}

extern "C" void kernel_launch(void* const* d_in, const int* in_sizes, int n_in,
                              void* d_out, int out_size, void* d_ws, size_t ws_size,
                              hipStream_t stream) {
  const int*   x   = (const int*)d_in[0];
  const float* emb = (const float*)d_in[1];
  const float* Wih = (const float*)d_in[2];
  const float* Whh = (const float*)d_in[3];
  const float* bih = (const float*)d_in[4];
  const float* bhh = (const float*)d_in[5];
  const float* Wa  = (const float*)d_in[6];
  // d_in[7] = ba: softmax is shift-invariant, so ba cancels exactly
  const float* W1  = (const float*)d_in[8];
  const float* b1  = (const float*)d_in[9];
  const float* W2  = (const float*)d_in[10];
  const float* b2  = (const float*)d_in[11];
  float* out = (float*)d_out;

  lstm_fused<<<512, 256, 0, stream>>>(x, emb, Wih, Whh, bih, bhh, Wa, W1, b1, W2, b2, out);
}

// Round 13
// 158.687 us; speedup vs baseline: 1.1379x; 1.1379x over previous
//
#include <hip/hip_runtime.h>

#define TSEQ 111
#define L2E 1.44269504088896340736f
#define TWO_L2E 2.88539008177792680472f

using f32x4  = __attribute__((ext_vector_type(4))) float;
using f32x2  = __attribute__((ext_vector_type(2))) float;
using short8 = __attribute__((ext_vector_type(8))) short;

union FragU { unsigned u[4]; uint4 v; short8 s; };

__device__ __forceinline__ float fexp2(float x) { return __builtin_amdgcn_exp2f(x); }
__device__ __forceinline__ float frcp(float x)  { return __builtin_amdgcn_rcpf(x); }
// tanh(z) given zs = z*log2(e)
__device__ __forceinline__ float tanh2(float zs) { return 1.f - 2.f * frcp(1.f + fexp2(zs + zs)); }
__device__ __forceinline__ f32x2 exp2v(f32x2 x) { f32x2 r; r[0] = fexp2(x[0]); r[1] = fexp2(x[1]); return r; }
__device__ __forceinline__ f32x2 rcpv(f32x2 x)  { f32x2 r; r[0] = frcp(x[0]); r[1] = frcp(x[1]); return r; }

// round-to-nearest-even bf16, value in LOW 16 bits
__device__ __forceinline__ unsigned rnd_bf16(float w) {
  unsigned u = __float_as_uint(w);
  return (u + 0x7fffu + ((u >> 16) & 1u)) >> 16;
}
// packed f32->bf16x2 in ONE instruction
__device__ __forceinline__ unsigned cvtpk(float a, float b) {
  unsigned r;
  asm("v_cvt_pk_bf16_f32 %0, %1, %2" : "=v"(r) : "v"(a), "v"(b));
  return r;
}

// R8 structure (best measured: 159.8 us). Block = 8 waves = 4 layers x 2 hidden-halves,
// 16 batch rows/block. SWAPPED-OPERAND gates: C = mfma(A=W-tile, B=h) -> C[unit][batch];
// lane's 4 outputs = 4 consecutive units of one batch row -> ONE ds_write_b64; store
// layout == next step's B-frag ds_read_b128 layout. 3 DS ops/wave/superstep.
// hb slots (bf16 [16 batch][32 units], 16B chunks XOR-swizzled by gcc(c)=(c&3)^(c>>2)):
//   slot k = h of layer k. Emb -> l0 B-frag regs direct from global (1 step ahead).
// Attention on l=3 pair reusing fh; per-lane scalar online softmax; zero cross-lane ops.
// Main-loop barrier = lgkmcnt-only (global prefetches stay in flight).
// R13 delta vs R8: the l3 softmax-update (register-only) moves AFTER the barrier, so the
// straggler wave no longer charges the other 7 waves its serial tail; it overlaps the
// next superstep's ds_read phase instead.
__global__ __launch_bounds__(512, 4) void lstm_fused(
    const int* __restrict__ x, const float* __restrict__ emb,
    const float* __restrict__ Wih, const float* __restrict__ Whh,
    const float* __restrict__ bih, const float* __restrict__ bhh,
    const float* __restrict__ Wa, const float* __restrict__ W1,
    const float* __restrict__ b1, const float* __restrict__ W2,
    const float* __restrict__ b2, float* __restrict__ out)
{
  __shared__ __align__(16) unsigned short hb[2 * 4 * 512];  // [parity][slot][16][32] bf16

  const int tid  = threadIdx.x;
  const int wvu  = __builtin_amdgcn_readfirstlane(tid) >> 6;  // wave id 0..7 (SGPR)
  const int l    = wvu >> 1;       // layer 0..3
  const int hf   = wvu & 1;        // hidden half
  const int lane = tid & 63;
  const int c    = lane & 15;      // batch row (B/C col); W-tile row (A)
  const int q    = lane >> 4;
  const int gcc  = (c & 3) ^ (c >> 2);   // chunk swizzle for row c
  const int rowbase = blockIdx.x * 16;
  const int xrow = (rowbase + c) * TSEQ;

  // lane-static LDS offsets (in shorts)
  const int rdOff = c * 32 + ((q ^ gcc) << 3);   // B-frag read: units 8q..8q+7 of batch c
  const int wrOff = c * 32 + ((((2 * hf + (q >> 1)) ^ gcc) << 3) | ((q & 1) << 2));

  // ---- weights -> register-resident bf16 A-fragments (RTN), sign/scale folded
  FragU wihf[4], whhf[4];
#pragma unroll
  for (int g = 0; g < 4; ++g) {
    const float sj = (g == 2) ? TWO_L2E : -L2E;
    const int wr = 32 * g + 16 * hf + c;          // gate-dim row
    const float* srcI = Wih + l * 4096 + wr * 32 + 8 * q;
    const float* srcH = Whh + l * 4096 + wr * 32 + 8 * q;
#pragma unroll
    for (int p = 0; p < 4; ++p) {
      wihf[g].u[p] = rnd_bf16(srcI[2 * p] * sj) | (rnd_bf16(srcI[2 * p + 1] * sj) << 16);
      whhf[g].u[p] = rnd_bf16(srcH[2 * p] * sj) | (rnd_bf16(srcH[2 * p + 1] * sj) << 16);
    }
  }
  // biases as f32x4 C-operands: elem e = bias of unit 16hf+4q+e, gate g
  f32x4 bvv[4];
#pragma unroll
  for (int g = 0; g < 4; ++g) {
    const float sj = (g == 2) ? TWO_L2E : -L2E;
    const int bi = l * 128 + 32 * g + 16 * hf + 4 * q;
#pragma unroll
    for (int e = 0; e < 4; ++e)
      bvv[g][e] = (bih[bi + e] + bhh[bi + e]) * sj;
  }

  // ---- Wa as A-frag replicated over rows (l==3 waves), hi/lo split, scaled by log2e
  FragU wahA, walA;
#pragma unroll
  for (int p = 0; p < 4; ++p) { wahA.u[p] = 0u; walA.u[p] = 0u; }
  if (l == 3) {
#pragma unroll
    for (int p = 0; p < 4; ++p) {
      const int k0 = 8 * q + 2 * p;
      float w0 = Wa[k0] * L2E, w1 = Wa[k0 + 1] * L2E;
      unsigned h0 = rnd_bf16(w0), h1b = rnd_bf16(w1);
      wahA.u[p] = h0 | (h1b << 16);
      float l0v = w0 - __uint_as_float(h0 << 16);
      float l1v = w1 - __uint_as_float(h1b << 16);
      walA.u[p] = rnd_bf16(l0v) | (rnd_bf16(l1v) << 16);
    }
  }

  // per-lane state: cells for units 16hf+4q+e, batch c; attention (l==3)
  f32x2 cs2[2];
  cs2[0] = (f32x2){0.f, 0.f}; cs2[1] = (f32x2){0.f, 0.f};
  float mr = -1e30f, sr = 0.f, cx[4];
#pragma unroll
  for (int e = 0; e < 4; ++e) cx[e] = 0.f;

  // ---- zero LDS
  for (int i = tid; i < 2 * 4 * 512 / 2; i += 512) ((unsigned*)hb)[i] = 0u;

  // ---- l0 prologue: emb(0) -> regs; idxn = token(1)
  float4 emA = make_float4(0.f, 0.f, 0.f, 0.f), emB = emA;
  int idxn = 0;
  if (l == 0) {
    int i0 = x[xrow];
    emA = *(const float4*)(emb + i0 * 32 + 8 * q);
    emB = *(const float4*)(emb + i0 * 32 + 8 * q + 4);
    idxn = x[xrow + 1];
  }
  __syncthreads();

#pragma unroll 2
  for (int s = 0; s < TSEQ + 4; ++s) {
    const int t = s - l;
    const bool active = ((unsigned)t < (unsigned)TSEQ);
    const int rp = (s + 1) & 1;   // read parity
    const int wp = s & 1;         // write parity
    const bool doAtt = (l == 3) && (s >= 4);

    // ---- B-fragment acquire
    FragU fi, fh;
    __builtin_amdgcn_s_setprio(1);
    if (active) {
      if (l == 0) {
        // build fi from prefetched emb regs; then issue loads for t+1
        fi.u[0] = cvtpk(emA.x, emA.y); fi.u[1] = cvtpk(emA.z, emA.w);
        fi.u[2] = cvtpk(emB.x, emB.y); fi.u[3] = cvtpk(emB.z, emB.w);
        if (t + 1 < TSEQ) {
          emA = *(const float4*)(emb + idxn * 32 + 8 * q);
          emB = *(const float4*)(emb + idxn * 32 + 8 * q + 4);
        }
        if (t + 2 < TSEQ) idxn = x[xrow + t + 2];
      } else {
        fi.v = *(const uint4*)(hb + (rp * 4 + (l - 1)) * 512 + rdOff);
      }
    }
    if (active || doAtt)
      fh.v = *(const uint4*)(hb + (rp * 4 + l) * 512 + rdOff);

    // ---- gate MFMAs: C[gate-unit][batch] = W*x + W*h + bias
    f32x4 acc[4];
    if (active) {
#pragma unroll
      for (int g = 0; g < 4; ++g) {
        acc[g] = __builtin_amdgcn_mfma_f32_16x16x32_bf16(wihf[g].s, fi.s, bvv[g], 0, 0, 0);
        acc[g] = __builtin_amdgcn_mfma_f32_16x16x32_bf16(whhf[g].s, fh.s, acc[g], 0, 0, 0);
      }
    }
    // ---- attention score MFMAs (l=3, reuses fh = h3(t-1) B-frag)
    f32x4 sacc;
    if (doAtt) {
      f32x4 z = {0.f, 0.f, 0.f, 0.f};
      sacc = __builtin_amdgcn_mfma_f32_16x16x32_bf16(wahA.s, fh.s, z, 0, 0, 0);
      sacc = __builtin_amdgcn_mfma_f32_16x16x32_bf16(walA.s, fh.s, sacc, 0, 0, 0);
    }
    __builtin_amdgcn_s_setprio(0);

    if (active) {
      // ---- gates (packed f32): acc0=-zi*l2e acc1=-zf*l2e acc2=+2zg*l2e acc3=-zo*l2e
      float hv[4];
      const f32x2 one = {1.f, 1.f};
      const f32x2 tl2 = {TWO_L2E, TWO_L2E};
#pragma unroll
      for (int pr2 = 0; pr2 < 2; ++pr2) {
        const int e0 = 2 * pr2;
        f32x2 va; va[0] = acc[0][e0]; va[1] = acc[0][e0 + 1];
        f32x2 vm; vm[0] = acc[1][e0]; vm[1] = acc[1][e0 + 1];
        f32x2 vb; vb[0] = acc[2][e0]; vb[1] = acc[2][e0 + 1];
        f32x2 vp; vp[0] = acc[3][e0]; vp[1] = acc[3][e0 + 1];
        f32x2 ea = exp2v(va), em_ = exp2v(vm), eb = exp2v(vb), ep = exp2v(vp);
        f32x2 P  = (one + ea) * (one + eb);
        f32x2 M1 = one + em_;
        f32x2 num = cs2[pr2] * P + (eb - one) * M1;
        f32x2 cn = num * rcpv(M1 * P);
        cs2[pr2] = cn;
        f32x2 qa = cn * tl2;
        qa[0] = fminf(qa[0], 80.f); qa[1] = fminf(qa[1], 80.f);
        f32x2 qv = exp2v(qa);
        f32x2 hvv = (qv - one) * rcpv((one + ep) * (one + qv));
        hv[e0] = hvv[0]; hv[e0 + 1] = hvv[1];
      }

      // ---- write h(t): units 16hf+4q..+3 of batch c -> ONE ds_write_b64
      *(uint2*)(hb + (wp * 4 + l) * 512 + wrOff) =
          make_uint2(cvtpk(hv[0], hv[1]), cvtpk(hv[2], hv[3]));
    }

    // lgkm-only barrier: LDS synced; global prefetches stay in flight
    asm volatile("s_waitcnt lgkmcnt(0)\n\ts_barrier" ::: "memory");

    // ---- attention online-softmax update: register-only, AFTER the barrier so the
    // l3 straggler tail overlaps the other waves' next-superstep ds_read phase.
    if (doAtt) {
      float pf = sacc[0];
      float mn = fmaxf(mr, pf);
      float sc = fexp2(mr - mn);
      float pr = fexp2(pf - mn);
      sr = sr * sc + pr;
      // this wave accumulates units 8q + 4hf .. +3 (elems 2hf,2hf+1 of fh)
#pragma unroll
      for (int p = 0; p < 2; ++p) {
        unsigned w = fh.u[2 * hf + p];
        cx[2 * p]     = cx[2 * p]     * sc + pr * __uint_as_float(w << 16);
        cx[2 * p + 1] = cx[2 * p + 1] * sc + pr * __uint_as_float(w & 0xffff0000u);
      }
      mr = mn;
    }
  }

  __syncthreads();

  // ---- context -> LDS (fp32 [16][33]); l=3 waves: batch c, units 8q+4hf+e
  float* cb = (float*)hb;
  if (l == 3) {
    float inv = frcp(sr);
#pragma unroll
    for (int e = 0; e < 4; ++e)
      cb[c * 33 + 8 * q + 4 * hf + e] = cx[e] * inv;
  }
  __syncthreads();
  if (wvu != 6) return;

  // ---- head (single wave): tanh MLP -> out
  float a0[4], a1[4];
  {
    float bb0 = b1[c], bb1 = b1[c + 16];
#pragma unroll
    for (int e = 0; e < 4; ++e) { a0[e] = bb0; a1[e] = bb1; }
    for (int j = 0; j < 32; ++j) {
      float w0 = W1[j * 32 + c];
      float w1 = W1[j * 32 + c + 16];
#pragma unroll
      for (int e = 0; e < 4; ++e) {
        float cr = cb[(4 * q + e) * 33 + j];
        a0[e] = fmaf(cr, w0, a0[e]);
        a1[e] = fmaf(cr, w1, a1[e]);
      }
    }
  }
  float o0[4], o1[4], o2[4];
  {
    float w20 = W2[c * 3 + 0], w21 = W2[c * 3 + 1], w22 = W2[c * 3 + 2];
    float w30 = W2[(c + 16) * 3 + 0], w31 = W2[(c + 16) * 3 + 1], w32 = W2[(c + 16) * 3 + 2];
#pragma unroll
    for (int e = 0; e < 4; ++e) {
      float h0 = tanh2(a0[e] * L2E);
      float hB = tanh2(a1[e] * L2E);
      o0[e] = h0 * w20 + hB * w30;
      o1[e] = h0 * w21 + hB * w31;
      o2[e] = h0 * w22 + hB * w32;
    }
  }
#pragma unroll
  for (int mk = 1; mk <= 8; mk <<= 1) {
#pragma unroll
    for (int e = 0; e < 4; ++e) {
      o0[e] += __shfl_xor(o0[e], mk, 64);
      o1[e] += __shfl_xor(o1[e], mk, 64);
      o2[e] += __shfl_xor(o2[e], mk, 64);
    }
  }
  if (c < 3) {
    float bb = b2[c];
#pragma unroll
    for (int e = 0; e < 4; ++e) {
      float v = (c == 0) ? o0[e] : ((c == 1) ? o1[e] : o2[e]);
      out[(rowbase + 4 * q + e) * 3 + c] = v + bb;
    }
  }
}

extern "C" void kernel_launch(void* const* d_in, const int* in_sizes, int n_in,
                              void* d_out, int out_size, void* d_ws, size_t ws_size,
                              hipStream_t stream) {
  const int*   x   = (const int*)d_in[0];
  const float* emb = (const float*)d_in[1];
  const float* Wih = (const float*)d_in[2];
  const float* Whh = (const float*)d_in[3];
  const float* bih = (const float*)d_in[4];
  const float* bhh = (const float*)d_in[5];
  const float* Wa  = (const float*)d_in[6];
  // d_in[7] = ba: softmax is shift-invariant, so ba cancels exactly
  const float* W1  = (const float*)d_in[8];
  const float* b1  = (const float*)d_in[9];
  const float* W2  = (const float*)d_in[10];
  const float* b2  = (const float*)d_in[11];
  float* out = (float*)d_out;

  lstm_fused<<<512, 512, 0, stream>>>(x, emb, Wih, Whh, bih, bhh, Wa, W1, b1, W2, b2, out);
}